// Round 1
// baseline (178.247 us; speedup 1.0000x reference)
//
#include <hip/hip_runtime.h>
#include <hip/hip_fp8.h>
#include <math.h>

typedef float v4f __attribute__((ext_vector_type(4)));

#define AS1 __attribute__((address_space(1)))
#define AS3 __attribute__((address_space(3)))

static constexpr int Bn = 8192;   // batch
static constexpr int Hn = 768;    // hidden
static constexpr float invB = 1.0f / 8192.0f;

__device__ __forceinline__ unsigned char cvt_e4m3(float x) {
    __hip_fp8_e4m3 t(x);          // OCP e4m3fn, RNE + satfinite
    return t.__x;
}

// tanh(x) = 1 - 2/(exp(2x)+1)
__device__ __forceinline__ float fast_tanh(float x) {
    float xc = fminf(fmaxf(x, -15.0f), 15.0f);
    float e = __expf(2.0f * xc);
    float r = __builtin_amdgcn_rcpf(e + 1.0f);
    return 1.0f - 2.0f * r;
}

// ---------------- fused prep: zero accumulators + fp32->fp8 all 5 tensors ----------------
__global__ void prep_kernel(const float* __restrict__ A,
                            const float* __restrict__ W1m, const float* __restrict__ W2m,
                            const float* __restrict__ W1v, const float* __restrict__ W2v,
                            unsigned char* __restrict__ A_f8,
                            unsigned char* __restrict__ W1m_f8, unsigned char* __restrict__ W2m_f8,
                            unsigned char* __restrict__ W1v_f8, unsigned char* __restrict__ W2v_f8,
                            float* __restrict__ zbuf, int nzero) {
    const int tid = blockIdx.x * blockDim.x + threadIdx.x;
    if (tid < nzero) zbuf[tid] = 0.0f;
    constexpr int A4 = Bn * Hn / 4;    // 4-elem units
    constexpr int W4 = Hn * Hn / 4;
    const int total = A4 + 4 * W4;
    const int stride = gridDim.x * blockDim.x;
    for (int i = tid; i < total; i += stride) {
        const float* s; unsigned char* d; int j;
        if (i < A4) { s = A; d = A_f8; j = i; }
        else {
            int k = i - A4; int w = k / W4; j = k - w * W4;
            s = (w == 0) ? W1m : (w == 1) ? W2m : (w == 2) ? W1v : W2v;
            d = (w == 0) ? W1m_f8 : (w == 1) ? W2m_f8 : (w == 2) ? W1v_f8 : W2v_f8;
        }
        float4 v = ((const float4*)s)[j];
        unsigned p = (unsigned)cvt_e4m3(v.x)
                   | ((unsigned)cvt_e4m3(v.y) << 8)
                   | ((unsigned)cvt_e4m3(v.z) << 16)
                   | ((unsigned)cvt_e4m3(v.w) << 24);
        ((unsigned*)d)[j] = p;
    }
}

// swizzle for 64B rows / 16B chunks: LDS[row][c] = GLOBAL[row][c ^ swz(row)]
__device__ __forceinline__ int swz4(int r) { return (r ^ (r >> 2)) & 3; }

// ---------------- LAYER 1: single-branch 128x128 tile, BK=64 double-buffered ----------------
// Operand swap (W as 'a') -> lane's 4 acc regs = 4 consecutive hidden dims of one batch row.
__device__ __forceinline__ void l1_compute(const unsigned char* bb_,
                                           int wm, int wn, int lr, int q1, int q2,
                                           v4f acc[4][4]) {
#pragma unroll
    for (int ks = 0; ks < 2; ++ks) {
        const int cg = ks * 2 + q2;
        long fb[4], fa[4];
#pragma unroll
        for (int mt = 0; mt < 4; ++mt) {
            int m = wm * 64 + mt * 16 + lr;
            fb[mt] = *(const long*)&bb_[m * 64 + ((cg ^ swz4(m)) << 4) + (q1 << 3)];
        }
#pragma unroll
        for (int nt = 0; nt < 4; ++nt) {
            int n = wn * 64 + nt * 16 + lr;
            fa[nt] = *(const long*)&bb_[8192 + n * 64 + ((cg ^ swz4(n)) << 4) + (q1 << 3)];
        }
#pragma unroll
        for (int nt = 0; nt < 4; ++nt)
#pragma unroll
            for (int mt = 0; mt < 4; ++mt)
                acc[nt][mt] = __builtin_amdgcn_mfma_f32_16x16x32_fp8_fp8(fa[nt], fb[mt], acc[nt][mt], 0, 0, 0);
    }
}

__launch_bounds__(256, 3)
__global__ void gemm_l1(const unsigned char* __restrict__ A_g,
                        const unsigned char* __restrict__ Wm_g, const unsigned char* __restrict__ Wv_g,
                        const float* __restrict__ bm, const float* __restrict__ bv,
                        unsigned char* __restrict__ outm, unsigned char* __restrict__ outv) {
    __shared__ __align__(16) unsigned char smem[32768];   // 2 bufs x (A 8K | W 8K)
    const int t = threadIdx.x;
    const int row0 = blockIdx.x * 128;     // batch
    const int col0 = blockIdx.y * 128;     // hidden
    const int br = blockIdx.z;             // 0 = mu branch, 1 = logvar branch
    const unsigned char* Wg = br ? Wv_g : Wm_g;
    const float* bias = br ? bv : bm;
    unsigned char* out = br ? outv : outm;

    const int w = t >> 6, lane = t & 63;
    const int wm = w >> 1, wn = w & 1;     // 2x2 waves, 64x64 per wave
    const int lr = lane & 15, quad = lane >> 4;
    const int q2 = quad >> 1, q1 = quad & 1;

    // staging: thread t -> row (t>>2), 16B chunk (t&3); XOR source chunk
    const int rst = t >> 2, cst = t & 3;
    const int csrc = cst ^ swz4(rst);

    const unsigned char* sA = A_g + (size_t)(row0 + rst) * Hn + csrc * 16;
    const unsigned char* sW = Wg  + (size_t)(col0 + rst) * Hn + csrc * 16;

    v4f acc[4][4] = {};   // [nt(hidden)][mt(batch)]

#define L1_STAGE(h_, nb_) do {                                                                                   \
    const int kb_ = (h_) * 64;                                                                                   \
    unsigned char* db_ = smem + (nb_) * 16384;                                                                   \
    __builtin_amdgcn_global_load_lds((const AS1 void*)(sA + kb_),           (AS3 void*)(db_ + t * 16), 16, 0, 0);          \
    __builtin_amdgcn_global_load_lds((const AS1 void*)(sA + 64 * Hn + kb_), (AS3 void*)(db_ + 4096 + t * 16), 16, 0, 0);   \
    __builtin_amdgcn_global_load_lds((const AS1 void*)(sW + kb_),           (AS3 void*)(db_ + 8192 + t * 16), 16, 0, 0);   \
    __builtin_amdgcn_global_load_lds((const AS1 void*)(sW + 64 * Hn + kb_), (AS3 void*)(db_ + 12288 + t * 16), 16, 0, 0);  \
  } while (0)

    L1_STAGE(0, 0);
    for (int h = 0; h < 11; ++h) {
        L1_STAGE(h + 1, (h + 1) & 1);                       // prefetch next half (4 loads)
        asm volatile("s_waitcnt vmcnt(4)" ::: "memory");    // current half landed; next stays in flight
        __builtin_amdgcn_s_barrier();
        __builtin_amdgcn_sched_barrier(0);
        l1_compute(smem + (h & 1) * 16384, wm, wn, lr, q1, q2, acc);
        __builtin_amdgcn_sched_barrier(0);
        __builtin_amdgcn_s_barrier();                       // all reads of this buf done before overwrite
    }
    asm volatile("s_waitcnt vmcnt(0)" ::: "memory");
    __builtin_amdgcn_s_barrier();
    __builtin_amdgcn_sched_barrier(0);
    l1_compute(smem + 16384, wm, wn, lr, q1, q2, acc);      // h = 11 -> buf1
    __syncthreads();
#undef L1_STAGE

    // epilogue: D row = quad*4+reg = hidden, D col = lane&15 = batch.
    // pack 4 hidden-consecutive fp8 -> dword, LDS transpose (pad 36 dw), coalesced 16B stores.
    unsigned* sm32 = (unsigned*)smem;
#pragma unroll
    for (int nt = 0; nt < 4; ++nt) {
        float4 bb = *(const float4*)&bias[col0 + wn * 64 + nt * 16 + quad * 4];
#pragma unroll
        for (int mt = 0; mt < 4; ++mt) {
            const int row_l = wm * 64 + mt * 16 + lr;   // batch row in tile
            v4f a = acc[nt][mt];
            unsigned p = (unsigned)cvt_e4m3(fast_tanh(a[0] + bb.x))
                       | ((unsigned)cvt_e4m3(fast_tanh(a[1] + bb.y)) << 8)
                       | ((unsigned)cvt_e4m3(fast_tanh(a[2] + bb.z)) << 16)
                       | ((unsigned)cvt_e4m3(fast_tanh(a[3] + bb.w)) << 24);
            sm32[row_l * 36 + wn * 16 + nt * 4 + quad] = p;
        }
    }
    __syncthreads();
#pragma unroll
    for (int i = 0; i < 4; ++i) {
        const int idx = i * 256 + t;
        const int row = idx >> 3, seg = idx & 7;
        uint4 d = *(const uint4*)&sm32[row * 36 + seg * 4];
        *(uint4*)&out[(size_t)(row0 + row) * Hn + col0 + seg * 16] = d;
    }
}

// ---------------- LAYER 2: branch-paired 64x128 tile, BK=64 dbuf, CLUB epilogue + finalize ----------------
__device__ __forceinline__ void l2_compute(const unsigned char* bb_,
                                           int wm, int wn, int lr, int q1, int q2,
                                           v4f accm[2][4], v4f accv[2][4]) {
#pragma unroll
    for (int ks = 0; ks < 2; ++ks) {
        const int cg = ks * 2 + q2;
        long fam[2], fav[2], fwm[4], fwv[4];
#pragma unroll
        for (int mt = 0; mt < 2; ++mt) {
            int m = wm * 32 + mt * 16 + lr;
            int off = m * 64 + ((cg ^ swz4(m)) << 4) + (q1 << 3);
            fam[mt] = *(const long*)&bb_[off];
            fav[mt] = *(const long*)&bb_[4096 + off];
        }
#pragma unroll
        for (int nt = 0; nt < 4; ++nt) {
            int n = wn * 64 + nt * 16 + lr;
            int off = n * 64 + ((cg ^ swz4(n)) << 4) + (q1 << 3);
            fwm[nt] = *(const long*)&bb_[8192 + off];
            fwv[nt] = *(const long*)&bb_[16384 + off];
        }
#pragma unroll
        for (int mt = 0; mt < 2; ++mt)
#pragma unroll
            for (int nt = 0; nt < 4; ++nt) {
                accm[mt][nt] = __builtin_amdgcn_mfma_f32_16x16x32_fp8_fp8(fam[mt], fwm[nt], accm[mt][nt], 0, 0, 0);
                accv[mt][nt] = __builtin_amdgcn_mfma_f32_16x16x32_fp8_fp8(fav[mt], fwv[nt], accv[mt][nt], 0, 0, 0);
            }
    }
}

__launch_bounds__(256, 3)
__global__ void gemm_l2(const unsigned char* __restrict__ Am_g, const unsigned char* __restrict__ Av_g,
                        const unsigned char* __restrict__ Wm_g, const unsigned char* __restrict__ Wv_g,
                        const float* __restrict__ bm, const float* __restrict__ bv,
                        const float* __restrict__ mb,
                        float* __restrict__ cs, float* __restrict__ cs2,
                        float* __restrict__ siv, float* __restrict__ sivmu,
                        float* __restrict__ accum, float* __restrict__ outp) {
    __shared__ __align__(16) unsigned char smem[49152];   // 2 bufs x (Am 4K | Av 4K | Wm 8K | Wv 8K)
    const int t = threadIdx.x;
    const int row0 = blockIdx.x * 64;      // batch
    const int col0 = blockIdx.y * 128;     // hidden
    const int w = t >> 6, lane = t & 63;
    const int wm = w >> 1, wn = w & 1;     // waves: 32(batch) x 64(hidden) each
    const int lr = lane & 15, quad = lane >> 4;
    const int q2 = quad >> 1, q1 = quad & 1;

    const int rst = t >> 2, cst = t & 3;
    const int csrc = cst ^ swz4(rst);

    const unsigned char* sAm = Am_g + (size_t)(row0 + rst) * Hn + csrc * 16;
    const unsigned char* sAv = Av_g + (size_t)(row0 + rst) * Hn + csrc * 16;
    const unsigned char* sWm = Wm_g + (size_t)(col0 + rst) * Hn + csrc * 16;
    const unsigned char* sWv = Wv_g + (size_t)(col0 + rst) * Hn + csrc * 16;

    v4f accm[2][4] = {}, accv[2][4] = {};   // [mt(batch)][nt(hidden)]

#define L2_STAGE(h_, nb_) do {                                                                                    \
    const int kb_ = (h_) * 64;                                                                                    \
    unsigned char* db_ = smem + (nb_) * 24576;                                                                    \
    __builtin_amdgcn_global_load_lds((const AS1 void*)(sAm + kb_),           (AS3 void*)(db_ + t * 16), 16, 0, 0);          \
    __builtin_amdgcn_global_load_lds((const AS1 void*)(sAv + kb_),           (AS3 void*)(db_ + 4096 + t * 16), 16, 0, 0);   \
    __builtin_amdgcn_global_load_lds((const AS1 void*)(sWm + kb_),           (AS3 void*)(db_ + 8192 + t * 16), 16, 0, 0);   \
    __builtin_amdgcn_global_load_lds((const AS1 void*)(sWm + 64 * Hn + kb_), (AS3 void*)(db_ + 12288 + t * 16), 16, 0, 0);  \
    __builtin_amdgcn_global_load_lds((const AS1 void*)(sWv + kb_),           (AS3 void*)(db_ + 16384 + t * 16), 16, 0, 0);  \
    __builtin_amdgcn_global_load_lds((const AS1 void*)(sWv + 64 * Hn + kb_), (AS3 void*)(db_ + 20480 + t * 16), 16, 0, 0);  \
  } while (0)

    L2_STAGE(0, 0);
    for (int h = 0; h < 11; ++h) {
        L2_STAGE(h + 1, (h + 1) & 1);                       // prefetch next half (6 loads)
        asm volatile("s_waitcnt vmcnt(6)" ::: "memory");    // current half landed; next stays in flight
        __builtin_amdgcn_s_barrier();
        __builtin_amdgcn_sched_barrier(0);
        l2_compute(smem + (h & 1) * 24576, wm, wn, lr, q1, q2, accm, accv);
        __builtin_amdgcn_sched_barrier(0);
        __builtin_amdgcn_s_barrier();
    }
    asm volatile("s_waitcnt vmcnt(0)" ::: "memory");
    __builtin_amdgcn_s_barrier();
    __builtin_amdgcn_sched_barrier(0);
    l2_compute(smem + 24576, wm, wn, lr, q1, q2, accm, accv);   // h = 11 -> buf1
#undef L2_STAGE

    // ---------------- CLUB epilogue: col=lane&15 (hidden), row=quad*4+r (batch) ----------------
    float pos = 0.f, q = 0.f;   // pos = sum iv*(mu-mb)^2 ; q = sum iv*mu^2
#pragma unroll
    for (int nt = 0; nt < 4; ++nt) {
        const int col = col0 + wn * 64 + nt * 16 + lr;
        const float bmc = bm[col], bvc = bv[col];
        float c1 = 0.f, c2 = 0.f, c3 = 0.f, c4 = 0.f;
#pragma unroll
        for (int mt = 0; mt < 2; ++mt) {
#pragma unroll
            for (int r = 0; r < 4; ++r) {
                const int row = row0 + wm * 32 + mt * 16 + quad * 4 + r;
                float mu = accm[mt][nt][r] + bmc;
                float tv = fast_tanh(accv[mt][nt][r] + bvc);
                float iv = __expf(-tv);
                float mbv = mb[(size_t)row * Hn + col];
                float d = mu - mbv;
                pos += iv * d * d;
                q   += iv * mu * mu;
                c1 += mu; c2 += mu * mu; c3 += iv; c4 += iv * mu;
            }
        }
        c1 += __shfl_xor(c1, 16); c1 += __shfl_xor(c1, 32);
        c2 += __shfl_xor(c2, 16); c2 += __shfl_xor(c2, 32);
        c3 += __shfl_xor(c3, 16); c3 += __shfl_xor(c3, 32);
        c4 += __shfl_xor(c4, 16); c4 += __shfl_xor(c4, 32);
        if (quad == 0) {
            atomicAdd(&cs[col], c1);
            atomicAdd(&cs2[col], c2);
            atomicAdd(&siv[col], c3);
            atomicAdd(&sivmu[col], c4);
        }
    }
    for (int off = 32; off > 0; off >>= 1) {
        pos += __shfl_down(pos, off);
        q   += __shfl_down(q, off);
    }
    __shared__ float redP[4], redQ[4];
    if (lane == 0) { redP[w] = pos; redQ[w] = q; }
    __syncthreads();
    __shared__ int is_last;
    if (t == 0) {
        atomicAdd(&accum[0], redP[0] + redP[1] + redP[2] + redP[3]);
        atomicAdd(&accum[1], redQ[0] + redQ[1] + redQ[2] + redQ[3]);
        __threadfence();
        unsigned old = atomicAdd((unsigned int*)&accum[3], 1u);
        is_last = (old == gridDim.x * gridDim.y - 1) ? 1 : 0;
    }
    __syncthreads();
    if (is_last) {
        float term = 0.f;
        for (int h = t; h < Hn; h += 256) {
            float v1 = atomicAdd(&cs[h], 0.0f);
            float v2 = atomicAdd(&cs2[h], 0.0f);
            float v3 = atomicAdd(&siv[h], 0.0f);
            float v4 = atomicAdd(&sivmu[h], 0.0f);
            term += v3 * v2 - 2.0f * v4 * v1;
        }
        for (int off = 32; off > 0; off >>= 1) term += __shfl_down(term, off);
        __shared__ float redT[4];
        if (lane == 0) redT[w] = term;
        __syncthreads();
        if (t == 0) {
            float T = redT[0] + redT[1] + redT[2] + redT[3];
            float P = atomicAdd(&accum[0], 0.0f);
            float Q = atomicAdd(&accum[1], 0.0f);
            float pos_sum = -0.5f * P;
            float neg_sum = -0.5f * (T * invB + Q);
            outp[0] = pos_sum * invB;
            outp[1] = (pos_sum - neg_sum) * invB;
        }
    }
}

extern "C" void kernel_launch(void* const* d_in, const int* in_sizes, int n_in,
                              void* d_out, int out_size, void* d_ws, size_t ws_size,
                              hipStream_t stream) {
    const float* modal_a = (const float*)d_in[0];
    const float* modal_b = (const float*)d_in[1];
    const float* W1m = (const float*)d_in[2];
    const float* b1m = (const float*)d_in[3];
    const float* W2m = (const float*)d_in[4];
    const float* b2m = (const float*)d_in[5];
    const float* W1v = (const float*)d_in[6];
    const float* b1v = (const float*)d_in[7];
    const float* W2v = (const float*)d_in[8];
    const float* b2v = (const float*)d_in[9];
    float* out = (float*)d_out;

    char* ws = (char*)d_ws;
    constexpr size_t szA8 = (size_t)Bn * Hn;       // fp8 [B,H] = 6.29 MB
    constexpr size_t szW8 = (size_t)Hn * Hn;       // fp8 [H,H] = 0.59 MB
    unsigned char* A_f8   = (unsigned char*)(ws);
    unsigned char* h1m_f8 = (unsigned char*)(ws + szA8);
    unsigned char* h1v_f8 = (unsigned char*)(ws + 2 * szA8);
    unsigned char* W1m_f8 = (unsigned char*)(ws + 3 * szA8);
    unsigned char* W2m_f8 = (unsigned char*)(ws + 3 * szA8 + szW8);
    unsigned char* W1v_f8 = (unsigned char*)(ws + 3 * szA8 + 2 * szW8);
    unsigned char* W2v_f8 = (unsigned char*)(ws + 3 * szA8 + 3 * szW8);
    float* cs     = (float*)(ws + 3 * szA8 + 4 * szW8);
    float* cs2    = cs + Hn;
    float* siv    = cs + 2 * Hn;
    float* sivmu  = cs + 3 * Hn;
    float* accum  = cs + 4 * Hn;   // [0]=P [1]=Q [2]=pad [3]=ticket

    // 1. fused zero + fp32->fp8 convert (A + 4 W)
    prep_kernel<<<1280, 256, 0, stream>>>(modal_a, W1m, W2m, W1v, W2v,
                                          A_f8, W1m_f8, W2m_f8, W1v_f8, W2v_f8,
                                          cs, 4 * Hn + 8);

    // 2. layer-1 fp8 GEMM, branch-split blocks (z = mu/logvar) -> h1{m,v} fp8
    gemm_l1<<<dim3(Bn / 128, Hn / 128, 2), 256, 0, stream>>>(
        A_f8, W1m_f8, W1v_f8, b1m, b1v, h1m_f8, h1v_f8);

    // 3. layer-2 fp8 paired GEMM (64x128 tiles) + CLUB epilogue + in-kernel finalize
    gemm_l2<<<dim3(Bn / 64, Hn / 128), 256, 0, stream>>>(
        h1m_f8, h1v_f8, W2m_f8, W2v_f8, b2m, b2v, modal_b,
        cs, cs2, siv, sivmu, accum, out);
}